// Round 5
// baseline (174.008 us; speedup 1.0000x reference)
//
#include <hip/hip_runtime.h>
#include <hip/hip_bf16.h>
#include <math.h>

#define NB 8
#define NS 1024
#define NT 1024
#define NE 256
#define NHEADS 8
#define DH 32

typedef __attribute__((ext_vector_type(8))) short short8;
typedef __attribute__((ext_vector_type(8))) unsigned short ushort8;
typedef __attribute__((ext_vector_type(4))) float f32x4;

// ws layout (byte offsets)
#define O_VT    0u                        // ushort[8][8][32][1024] V^T swizzled
#define O_AGGB  (4u<<20)                  // ushort[8192*256] agg bf16 [s][hd]
#define O_WTT   (8u<<20)                  // ushort[256*256] W_trg^T bf16 [n][k]
#define O_WTO   ((8u<<20)+131072u)        // ushort[256*256] W_out^T bf16 [n][k]
#define O_CSRC  ((8u<<20)+262144u)        // float[8*256]
#define O_CTRG  (O_CSRC+8192u)
#define O_SSRC  (O_CTRG+8192u)            // float[8192*8]
#define O_STRG  (O_SSRC+262144u)          // float[8192*8]
#define O_FLAG  (O_STRG+262144u)          // int

__device__ __forceinline__ unsigned short f2bf(float f) {
    __hip_bfloat16 h = __float2bfloat16(f);
    union { __hip_bfloat16 h; unsigned short u; } c; c.h = h;
    return c.u;
}
__device__ __forceinline__ float bf2f(unsigned short u) {
    union { unsigned u; float f; } x; x.u = ((unsigned)u) << 16;
    return x.f;
}

// ---------------------------------------------------------------------------
// Kernel A: bid0 = mask-layout probe; bid1/2 = c_src/c_trg (f32, exact);
// bid3..34 = W_trg/W_out 64x64 LDS-tile transposes -> bf16 [n][k], coalesced.
// ---------------------------------------------------------------------------
__global__ __launch_bounds__(256) void setup_kernel(
    const unsigned* __restrict__ tmask_dw, const float* __restrict__ Wsrc,
    const float* __restrict__ Wtrg, const float* __restrict__ Wout,
    const float* __restrict__ asrc, const float* __restrict__ atrg,
    float* __restrict__ c_src, float* __restrict__ c_trg,
    unsigned short* __restrict__ Wt_t, unsigned short* __restrict__ Wt_o,
    int* __restrict__ flag) {
    __shared__ __align__(16) char sm[16640];
    const int tid = threadIdx.x;
    const int bid = blockIdx.x;

    if (bid == 0) {
        __shared__ int s_ok;
        if (tid == 0) s_ok = 1;
        __syncthreads();
        for (int i = tid; i < 2048; i += 256)
            if (tmask_dw[i] > 1u) s_ok = 0;
        __syncthreads();
        if (tid == 0) *flag = s_ok;
    } else if (bid <= 2) {
        float* a_sh = (float*)sm;
        const float* W = (bid == 1) ? Wsrc : Wtrg;
        const float* a = (bid == 1) ? asrc : atrg;
        float* c = (bid == 1) ? c_src : c_trg;
        a_sh[tid] = a[tid];
        __syncthreads();
        const int e = tid;
        float ch[8];
#pragma unroll
        for (int h = 0; h < 8; ++h) ch[h] = 0.f;
        for (int i = 0; i < 64; ++i) {
            const float4 wv = *(const float4*)&W[(size_t)e * NE + i * 4];
            const int h = i >> 3, d0 = (i & 7) * 4;
            ch[h] += wv.x * a_sh[h * 32 + d0] + wv.y * a_sh[h * 32 + d0 + 1] +
                     wv.z * a_sh[h * 32 + d0 + 2] + wv.w * a_sh[h * 32 + d0 + 3];
        }
#pragma unroll
        for (int h = 0; h < 8; ++h) c[h * NE + e] = ch[h];
    } else {
        const int q = bid - 3;                    // 0..31
        const float* W = (q >> 4) ? Wout : Wtrg;
        unsigned short* Wt = (q >> 4) ? Wt_o : Wt_t;
        const int tl = q & 15;
        const int k0 = (tl >> 2) * 64, n0 = (tl & 3) * 64;
        float* xs = (float*)sm;                   // [64][65]
#pragma unroll
        for (int it = 0; it < 4; ++it) {
            const int slot = it * 256 + tid;      // 1024 float4 slots
            const int k = slot >> 4, c4 = slot & 15;
            const float4 v = *(const float4*)&W[(size_t)(k0 + k) * NE + n0 + c4 * 4];
            float* p = &xs[k * 65 + c4 * 4];
            p[0] = v.x; p[1] = v.y; p[2] = v.z; p[3] = v.w;
        }
        __syncthreads();
#pragma unroll
        for (int it = 0; it < 2; ++it) {
            const int slot = it * 256 + tid;      // 512 slots
            const int n = slot >> 3, kc = slot & 7;
            ushort8 v;
#pragma unroll
            for (int e = 0; e < 8; ++e)
                v[e] = f2bf(xs[(kc * 8 + e) * 65 + n]);
            *(ushort8*)&Wt[(size_t)(n0 + n) * NE + k0 + kc * 8] = v;
        }
    }
}

// ---------------------------------------------------------------------------
// Kernel B: bid<256 -> V gemm (trg @ W_trg, bf16 MFMA) with LDS-transpose
// epilogue writing V^T swizzled to global Vt[b][h][d][t^((d&7)<<3)];
// bid>=256 -> score rows (src@c_src / trg@c_trg), exact f32.
// ---------------------------------------------------------------------------
__global__ __launch_bounds__(256) void mid_kernel(
    const float* __restrict__ src, const float* __restrict__ trg,
    const float* __restrict__ c_src, const float* __restrict__ c_trg,
    const unsigned short* __restrict__ Wt_t, unsigned short* __restrict__ Vt,
    float* __restrict__ ssrc, float* __restrict__ strg) {
    __shared__ __align__(16) char sm[49152];
    const int tid = threadIdx.x;
    const int bid = blockIdx.x;

    if (bid < 256) {
        unsigned short* As = (unsigned short*)sm;            // [64][256]
        unsigned short* ldsT = (unsigned short*)(sm + 32768); // [128][64]
        const int lane = tid & 63, w = tid >> 6;
        const int row0 = (bid >> 1) * 64;
        const int col0 = (bid & 1) * 128;

#pragma unroll
        for (int it = 0; it < 8; ++it) {
            const int gf = it * 256 + tid;
            const int row = gf >> 5, g3 = gf & 31;
            const float4 a = *(const float4*)&trg[(size_t)(row0 + row) * NE + g3 * 8];
            const float4 b = *(const float4*)&trg[(size_t)(row0 + row) * NE + g3 * 8 + 4];
            ushort8 v;
            v[0] = f2bf(a.x); v[1] = f2bf(a.y); v[2] = f2bf(a.z); v[3] = f2bf(a.w);
            v[4] = f2bf(b.x); v[5] = f2bf(b.y); v[6] = f2bf(b.z); v[7] = f2bf(b.w);
            *(ushort8*)&As[row * NE + ((g3 ^ (row & 7)) * 8)] = v;
        }
        __syncthreads();

        const int r = lane & 15, g = lane >> 4;
        short8 af[8];
#pragma unroll
        for (int kk = 0; kk < 8; ++kk)
            af[kk] = *(const short8*)&As[(w * 16 + r) * NE + (((kk * 4 + g) ^ (r & 7)) * 8)];

        f32x4 acc[8];
#pragma unroll
        for (int nt = 0; nt < 8; ++nt) acc[nt] = (f32x4){0.f, 0.f, 0.f, 0.f};
#pragma unroll
        for (int kk = 0; kk < 8; ++kk) {
#pragma unroll
            for (int nt = 0; nt < 8; ++nt) {
                const int col = col0 + nt * 16 + r;
                const short8 bf = *(const short8*)&Wt_t[(size_t)col * NE + kk * 32 + g * 8];
                acc[nt] = __builtin_amdgcn_mfma_f32_16x16x32_bf16(af[kk], bf, acc[nt], 0, 0, 0);
            }
        }
        __syncthreads();   // As reads done; ldsT region reused below

        // transpose epilogue: ldsT[col][t ^ ((col&7)<<3)] = bf16(acc)
#pragma unroll
        for (int nt = 0; nt < 8; ++nt) {
            const int cl = nt * 16 + r;
            const int sw = (cl & 7) << 3;
#pragma unroll
            for (int j = 0; j < 4; ++j) {
                const int t = w * 16 + g * 4 + j;
                ldsT[cl * 64 + (t ^ sw)] = f2bf(acc[nt][j]);
            }
        }
        __syncthreads();

        const int b = row0 >> 10, t0 = row0 & 1023;
#pragma unroll
        for (int it = 0; it < 4; ++it) {
            const int slot = it * 256 + tid;      // 1024 chunks
            const int cl = slot >> 3, ch = slot & 7;
            const int colg = col0 + cl;
            const int h = colg >> 5, d = colg & 31;
            *(ushort8*)&Vt[(((size_t)(b * 8 + h)) * 32 + d) * 1024 + t0 + ch * 8] =
                *(const ushort8*)&ldsT[cl * 64 + ch * 8];
        }
    } else {
        float* xs = (float*)sm;                  // [32][256]
        float* cs = (float*)(sm + 32768);        // [8][256]
        const int rowg0 = (bid - 256) * 32;
        const bool is_src = rowg0 < NB * NS;
        const float* X = is_src ? (src + (size_t)rowg0 * NE)
                                : (trg + (size_t)(rowg0 - NB * NS) * NE);
        const float* C = is_src ? c_src : c_trg;
        float* S = is_src ? (ssrc + (size_t)rowg0 * NHEADS)
                          : (strg + (size_t)(rowg0 - NB * NS) * NHEADS);

#pragma unroll
        for (int it = 0; it < 8; ++it) {
            const int slot = it * 256 + tid;     // float4 slots
            const int row = slot >> 6, c4 = slot & 63;
            *(float4*)&xs[row * NE + c4 * 4] =
                *(const float4*)&X[(size_t)row * NE + c4 * 4];
            cs[slot] = C[slot];
        }
        __syncthreads();

        const int r = tid >> 3, h = tid & 7;
        float s = 0.f;
        for (int e = 0; e < NE; e += 4) {
            const float4 x = *(const float4*)&xs[r * NE + e];
            const float4 c = *(const float4*)&cs[h * NE + e];
            s += x.x * c.x + x.y * c.y + x.z * c.z + x.w * c.w;
        }
        S[(size_t)r * NHEADS + h] = s;
    }
}

// ---------------------------------------------------------------------------
// Kernel C: fused softmax + attn write + aggregation. V staged by pure linear
// 64KB copy (Vt is pre-transposed + pre-swizzled). Unnormalized p kept bf16
// in regs; MFMA; epilogue scales by 1/sum. Nontemporal attn stores.
// ---------------------------------------------------------------------------
__global__ __launch_bounds__(256) void fused_softmax_agg_kernel(
    const float* __restrict__ ssrc, const float* __restrict__ strg,
    const void* __restrict__ smask, const void* __restrict__ tmask,
    const int* __restrict__ flag_p, const unsigned short* __restrict__ Vt,
    float* __restrict__ attn, unsigned short* __restrict__ agg_bf) {
    const int blk = blockIdx.x;
    const int stile = blk & 15;
    const int h = (blk >> 4) & 7;
    const int b = blk >> 7;
    const int tid = threadIdx.x;
    const int lane = tid & 63;
    const int wave = tid >> 6;
    const int flag = *flag_p;

    __shared__ __align__(16) float s_sm[NT];
    __shared__ __align__(16) unsigned short vt[32 * 1024];
    __shared__ float s_inv[64];

    const unsigned short* vsrc = Vt + (size_t)(b * NHEADS + h) * 32768;
#pragma unroll
    for (int it = 0; it < 16; ++it) {
        const int off = (it * 256 + tid) * 8;
        *(ushort8*)&vt[off] = *(const ushort8*)&vsrc[off];
    }
    for (int t = tid; t < NT; t += 256) {
        const bool mv = flag ? (((const int*)tmask)[b * NT + t] != 0)
                             : (((const unsigned char*)tmask)[b * NT + t] != 0);
        s_sm[t] = mv ? strg[((size_t)b * NT + t) * NHEADS + h] : -1e30f;
    }
    __syncthreads();

    const int r = lane & 15;
    const int g = lane >> 4;
    const int srow = stile * 64 + wave * 16 + r;
    const float ss = ssrc[((size_t)b * NS + srow) * NHEADS + h];
    const bool rowv = flag ? (((const int*)smask)[b * NS + srow] != 0)
                           : (((const unsigned char*)smask)[b * NS + srow] != 0);
    const int sw = (r & 7) << 3;
    const unsigned short* vr0 = vt + r * 1024;
    const unsigned short* vr1 = vt + (r + 16) * 1024;

    short8 preg[32];
    f32x4 acc0 = {0.f, 0.f, 0.f, 0.f};
    f32x4 acc1 = {0.f, 0.f, 0.f, 0.f};
    float sum = 0.f;

#pragma unroll
    for (int c = 0; c < 32; ++c) {
        const int tb = c * 32 + g * 8;
        const float4 v0 = *(const float4*)&s_sm[tb];
        const float4 v1 = *(const float4*)&s_sm[tb + 4];
        const float vv[8] = {v0.x, v0.y, v0.z, v0.w, v1.x, v1.y, v1.z, v1.w};
        short8 pa;
#pragma unroll
        for (int e = 0; e < 8; ++e) {
            float v = ss + vv[e];
            v = (v >= 0.f) ? v : 0.2f * v;
            const float p = __expf(v);
            sum += p;
            pa[e] = (short)f2bf(p);
        }
        preg[c] = pa;
        const short8 b0 = *(const short8*)&vr0[tb ^ sw];
        const short8 b1 = *(const short8*)&vr1[tb ^ sw];
        acc0 = __builtin_amdgcn_mfma_f32_16x16x32_bf16(pa, b0, acc0, 0, 0, 0);
        acc1 = __builtin_amdgcn_mfma_f32_16x16x32_bf16(pa, b1, acc1, 0, 0, 0);
    }

    sum += __shfl_xor(sum, 16);
    sum += __shfl_xor(sum, 32);
    const float inv = (rowv && sum > 0.f) ? 1.f / sum : 0.f;
    if (g == 0) s_inv[wave * 16 + r] = inv;

    float* arow = attn + ((size_t)((b * NHEADS + h) * NS) + srow) * NT;
#pragma unroll
    for (int c = 0; c < 32; ++c) {
        const int tb = c * 32 + g * 8;
        f32x4 o0, o1;
#pragma unroll
        for (int e = 0; e < 4; ++e) {
            o0[e] = bf2f((unsigned short)preg[c][e]) * inv;
            o1[e] = bf2f((unsigned short)preg[c][e + 4]) * inv;
        }
        __builtin_nontemporal_store(o0, (f32x4*)(arow + tb));
        __builtin_nontemporal_store(o1, (f32x4*)(arow + tb + 4));
    }

    __syncthreads();
    const int orow = stile * 64 + wave * 16 + g * 4;
    unsigned short* ab = agg_bf + ((size_t)b * NS + orow) * NE + h * DH + r;
#pragma unroll
    for (int j = 0; j < 4; ++j) {
        const float iv = s_inv[wave * 16 + g * 4 + j];
        ab[(size_t)j * NE] = f2bf(acc0[j] * iv);
        ab[(size_t)j * NE + 16] = f2bf(acc1[j] * iv);
    }
}

// ---------------------------------------------------------------------------
// Kernel D: out = agg_bf @ W_out (bf16 MFMA, f32 out).
// ---------------------------------------------------------------------------
__global__ __launch_bounds__(256) void gemm_out_kernel(
    const unsigned short* __restrict__ Xb, const unsigned short* __restrict__ Wt,
    float* __restrict__ Yf) {
    __shared__ __align__(16) unsigned short As[64 * NE];
    const int tid = threadIdx.x;
    const int lane = tid & 63;
    const int w = tid >> 6;
    const int row0 = blockIdx.x * 64;
    const int col0 = blockIdx.y * 128;

#pragma unroll
    for (int it = 0; it < 8; ++it) {
        const int gf = it * 256 + tid;
        const int row = gf >> 5, g3 = gf & 31;
        const ushort8 v = *(const ushort8*)&Xb[(size_t)(row0 + row) * NE + g3 * 8];
        *(ushort8*)&As[row * NE + ((g3 ^ (row & 7)) * 8)] = v;
    }
    __syncthreads();

    const int r = lane & 15, g = lane >> 4;
    short8 af[8];
#pragma unroll
    for (int kk = 0; kk < 8; ++kk)
        af[kk] = *(const short8*)&As[(w * 16 + r) * NE + (((kk * 4 + g) ^ (r & 7)) * 8)];

    f32x4 acc[8];
#pragma unroll
    for (int nt = 0; nt < 8; ++nt) acc[nt] = (f32x4){0.f, 0.f, 0.f, 0.f};
#pragma unroll
    for (int kk = 0; kk < 8; ++kk) {
#pragma unroll
        for (int nt = 0; nt < 8; ++nt) {
            const int col = col0 + nt * 16 + r;
            const short8 bf = *(const short8*)&Wt[(size_t)col * NE + kk * 32 + g * 8];
            acc[nt] = __builtin_amdgcn_mfma_f32_16x16x32_bf16(af[kk], bf, acc[nt], 0, 0, 0);
        }
    }

#pragma unroll
    for (int nt = 0; nt < 8; ++nt) {
        const int col = col0 + nt * 16 + r;
#pragma unroll
        for (int j = 0; j < 4; ++j) {
            const int row = row0 + w * 16 + g * 4 + j;
            Yf[(size_t)row * NE + col] = acc[nt][j];
        }
    }
}

extern "C" void kernel_launch(void* const* d_in, const int* in_sizes, int n_in,
                              void* d_out, int out_size, void* d_ws, size_t ws_size,
                              hipStream_t stream) {
    const float* src   = (const float*)d_in[0];
    const float* trg   = (const float*)d_in[1];
    const void*  smask = d_in[2];
    const void*  tmask = d_in[3];
    const float* Wsrc  = (const float*)d_in[4];
    const float* Wtrg  = (const float*)d_in[5];
    const float* asrc  = (const float*)d_in[6];
    const float* atrg  = (const float*)d_in[7];
    const float* Wout  = (const float*)d_in[8];

    float* out  = (float*)d_out;
    float* attn = out + (size_t)NB * NS * NE;

    char* wsb = (char*)d_ws;
    unsigned short* Vt     = (unsigned short*)(wsb + O_VT);
    unsigned short* agg_bf = (unsigned short*)(wsb + O_AGGB);
    unsigned short* Wt_t   = (unsigned short*)(wsb + O_WTT);
    unsigned short* Wt_o   = (unsigned short*)(wsb + O_WTO);
    float* c_src = (float*)(wsb + O_CSRC);
    float* c_trg = (float*)(wsb + O_CTRG);
    float* ssrc  = (float*)(wsb + O_SSRC);
    float* strg  = (float*)(wsb + O_STRG);
    int*   flag  = (int*)(wsb + O_FLAG);

    setup_kernel<<<35, 256, 0, stream>>>(
        (const unsigned*)tmask, Wsrc, Wtrg, Wout, asrc, atrg,
        c_src, c_trg, Wt_t, Wt_o, flag);

    mid_kernel<<<768, 256, 0, stream>>>(
        src, trg, c_src, c_trg, Wt_t, Vt, ssrc, strg);

    fused_softmax_agg_kernel<<<NB * NHEADS * (NS / 64), 256, 0, stream>>>(
        ssrc, strg, smask, tmask, flag, Vt, attn, agg_bf);

    gemm_out_kernel<<<dim3(128, 2), 256, 0, stream>>>(agg_bf, Wt_o, out);
}

// Round 6
// 112.252 us; speedup vs baseline: 1.5502x; 1.5502x over previous
//
#include <hip/hip_runtime.h>
#include <hip/hip_bf16.h>
#include <math.h>

#define NB 8
#define NS 1024
#define NT 1024
#define NE 256
#define NHEADS 8
#define DH 32

typedef __attribute__((ext_vector_type(8))) short short8;
typedef __attribute__((ext_vector_type(8))) unsigned short ushort8;
typedef __attribute__((ext_vector_type(4))) float f32x4;

// ws layout (byte offsets)
#define O_VT    0u                        // ushort[8][8][32][1024] V^T swizzled
#define O_AGGB  (4u<<20)                  // ushort[8192*256] agg bf16 [s][hd]
#define O_WTT   (8u<<20)                  // ushort[256*256] W_trg^T bf16 [n][k]
#define O_WTO   ((8u<<20)+131072u)        // ushort[256*256] W_out^T bf16 [n][k]
#define O_CSRC  ((8u<<20)+262144u)        // float[8*256]
#define O_CTRG  (O_CSRC+8192u)
#define O_SSRC  (O_CTRG+8192u)            // float[8192*8]
#define O_STRG  (O_SSRC+262144u)          // float[8192*8]
#define O_FLAG  (O_STRG+262144u)          // int

__device__ __forceinline__ unsigned short f2bf(float f) {
    __hip_bfloat16 h = __float2bfloat16(f);
    union { __hip_bfloat16 h; unsigned short u; } c; c.h = h;
    return c.u;
}
__device__ __forceinline__ float bf2f(unsigned short u) {
    union { unsigned u; float f; } x; x.u = ((unsigned)u) << 16;
    return x.f;
}

// ---------------------------------------------------------------------------
// Kernel A: bid0 = mask-layout probe; bid1/2 = c_src/c_trg (f32, exact);
// bid3..34 = W_trg/W_out 64x64 LDS-tile transposes -> bf16 [n][k], coalesced.
// ---------------------------------------------------------------------------
__global__ __launch_bounds__(256) void setup_kernel(
    const unsigned* __restrict__ tmask_dw, const float* __restrict__ Wsrc,
    const float* __restrict__ Wtrg, const float* __restrict__ Wout,
    const float* __restrict__ asrc, const float* __restrict__ atrg,
    float* __restrict__ c_src, float* __restrict__ c_trg,
    unsigned short* __restrict__ Wt_t, unsigned short* __restrict__ Wt_o,
    int* __restrict__ flag) {
    __shared__ __align__(16) char sm[16640];
    const int tid = threadIdx.x;
    const int bid = blockIdx.x;

    if (bid == 0) {
        __shared__ int s_ok;
        if (tid == 0) s_ok = 1;
        __syncthreads();
        for (int i = tid; i < 2048; i += 256)
            if (tmask_dw[i] > 1u) s_ok = 0;
        __syncthreads();
        if (tid == 0) *flag = s_ok;
    } else if (bid <= 2) {
        float* a_sh = (float*)sm;
        const float* W = (bid == 1) ? Wsrc : Wtrg;
        const float* a = (bid == 1) ? asrc : atrg;
        float* c = (bid == 1) ? c_src : c_trg;
        a_sh[tid] = a[tid];
        __syncthreads();
        const int e = tid;
        float ch[8];
#pragma unroll
        for (int h = 0; h < 8; ++h) ch[h] = 0.f;
        for (int i = 0; i < 64; ++i) {
            const float4 wv = *(const float4*)&W[(size_t)e * NE + i * 4];
            const int h = i >> 3, d0 = (i & 7) * 4;
            ch[h] += wv.x * a_sh[h * 32 + d0] + wv.y * a_sh[h * 32 + d0 + 1] +
                     wv.z * a_sh[h * 32 + d0 + 2] + wv.w * a_sh[h * 32 + d0 + 3];
        }
#pragma unroll
        for (int h = 0; h < 8; ++h) c[h * NE + e] = ch[h];
    } else {
        const int q = bid - 3;                    // 0..31
        const float* W = (q >> 4) ? Wout : Wtrg;
        unsigned short* Wt = (q >> 4) ? Wt_o : Wt_t;
        const int tl = q & 15;
        const int k0 = (tl >> 2) * 64, n0 = (tl & 3) * 64;
        float* xs = (float*)sm;                   // [64][65]
#pragma unroll
        for (int it = 0; it < 4; ++it) {
            const int slot = it * 256 + tid;      // 1024 float4 slots
            const int k = slot >> 4, c4 = slot & 15;
            const float4 v = *(const float4*)&W[(size_t)(k0 + k) * NE + n0 + c4 * 4];
            float* p = &xs[k * 65 + c4 * 4];
            p[0] = v.x; p[1] = v.y; p[2] = v.z; p[3] = v.w;
        }
        __syncthreads();
#pragma unroll
        for (int it = 0; it < 2; ++it) {
            const int slot = it * 256 + tid;      // 512 slots
            const int n = slot >> 3, kc = slot & 7;
            ushort8 v;
#pragma unroll
            for (int e = 0; e < 8; ++e)
                v[e] = f2bf(xs[(kc * 8 + e) * 65 + n]);
            *(ushort8*)&Wt[(size_t)(n0 + n) * NE + k0 + kc * 8] = v;
        }
    }
}

// ---------------------------------------------------------------------------
// Kernel B: bid<256 -> V gemm (trg @ W_trg, bf16 MFMA) with LDS-transpose
// epilogue writing V^T swizzled to global Vt[b][h][d][t^((d&7)<<3)];
// bid>=256 -> score rows (src@c_src / trg@c_trg), exact f32.
// ---------------------------------------------------------------------------
__global__ __launch_bounds__(256) void mid_kernel(
    const float* __restrict__ src, const float* __restrict__ trg,
    const float* __restrict__ c_src, const float* __restrict__ c_trg,
    const unsigned short* __restrict__ Wt_t, unsigned short* __restrict__ Vt,
    float* __restrict__ ssrc, float* __restrict__ strg) {
    __shared__ __align__(16) char sm[49152];
    const int tid = threadIdx.x;
    const int bid = blockIdx.x;

    if (bid < 256) {
        unsigned short* As = (unsigned short*)sm;            // [64][256]
        unsigned short* ldsT = (unsigned short*)(sm + 32768); // [128][64]
        const int lane = tid & 63, w = tid >> 6;
        const int row0 = (bid >> 1) * 64;
        const int col0 = (bid & 1) * 128;

#pragma unroll
        for (int it = 0; it < 8; ++it) {
            const int gf = it * 256 + tid;
            const int row = gf >> 5, g3 = gf & 31;
            const float4 a = *(const float4*)&trg[(size_t)(row0 + row) * NE + g3 * 8];
            const float4 b = *(const float4*)&trg[(size_t)(row0 + row) * NE + g3 * 8 + 4];
            ushort8 v;
            v[0] = f2bf(a.x); v[1] = f2bf(a.y); v[2] = f2bf(a.z); v[3] = f2bf(a.w);
            v[4] = f2bf(b.x); v[5] = f2bf(b.y); v[6] = f2bf(b.z); v[7] = f2bf(b.w);
            *(ushort8*)&As[row * NE + ((g3 ^ (row & 7)) * 8)] = v;
        }
        __syncthreads();

        const int r = lane & 15, g = lane >> 4;
        short8 af[8];
#pragma unroll
        for (int kk = 0; kk < 8; ++kk)
            af[kk] = *(const short8*)&As[(w * 16 + r) * NE + (((kk * 4 + g) ^ (r & 7)) * 8)];

        f32x4 acc[8];
#pragma unroll
        for (int nt = 0; nt < 8; ++nt) acc[nt] = (f32x4){0.f, 0.f, 0.f, 0.f};
#pragma unroll
        for (int kk = 0; kk < 8; ++kk) {
#pragma unroll
            for (int nt = 0; nt < 8; ++nt) {
                const int col = col0 + nt * 16 + r;
                const short8 bf = *(const short8*)&Wt_t[(size_t)col * NE + kk * 32 + g * 8];
                acc[nt] = __builtin_amdgcn_mfma_f32_16x16x32_bf16(af[kk], bf, acc[nt], 0, 0, 0);
            }
        }
        __syncthreads();   // As reads done; ldsT region reused below

        // transpose epilogue: ldsT[col][t ^ ((col&7)<<3)] = bf16(acc)
#pragma unroll
        for (int nt = 0; nt < 8; ++nt) {
            const int cl = nt * 16 + r;
            const int sw = (cl & 7) << 3;
#pragma unroll
            for (int j = 0; j < 4; ++j) {
                const int t = w * 16 + g * 4 + j;
                ldsT[cl * 64 + (t ^ sw)] = f2bf(acc[nt][j]);
            }
        }
        __syncthreads();

        const int b = row0 >> 10, t0 = row0 & 1023;
#pragma unroll
        for (int it = 0; it < 4; ++it) {
            const int slot = it * 256 + tid;      // 1024 chunks
            const int cl = slot >> 3, ch = slot & 7;
            const int colg = col0 + cl;
            const int h = colg >> 5, d = colg & 31;
            *(ushort8*)&Vt[(((size_t)(b * 8 + h)) * 32 + d) * 1024 + t0 + ch * 8] =
                *(const ushort8*)&ldsT[cl * 64 + ch * 8];
        }
    } else {
        float* xs = (float*)sm;                  // [32][256]
        float* cs = (float*)(sm + 32768);        // [8][256]
        const int rowg0 = (bid - 256) * 32;
        const bool is_src = rowg0 < NB * NS;
        const float* X = is_src ? (src + (size_t)rowg0 * NE)
                                : (trg + (size_t)(rowg0 - NB * NS) * NE);
        const float* C = is_src ? c_src : c_trg;
        float* S = is_src ? (ssrc + (size_t)rowg0 * NHEADS)
                          : (strg + (size_t)(rowg0 - NB * NS) * NHEADS);

#pragma unroll
        for (int it = 0; it < 8; ++it) {
            const int slot = it * 256 + tid;     // float4 slots
            const int row = slot >> 6, c4 = slot & 63;
            *(float4*)&xs[row * NE + c4 * 4] =
                *(const float4*)&X[(size_t)row * NE + c4 * 4];
            cs[slot] = C[slot];
        }
        __syncthreads();

        const int r = tid >> 3, h = tid & 7;
        float s = 0.f;
        for (int e = 0; e < NE; e += 4) {
            const float4 x = *(const float4*)&xs[r * NE + e];
            const float4 c = *(const float4*)&cs[h * NE + e];
            s += x.x * c.x + x.y * c.y + x.z * c.z + x.w * c.w;
        }
        S[(size_t)r * NHEADS + h] = s;
    }
}

// ---------------------------------------------------------------------------
// Kernel C: fused softmax + attn write + aggregation. V staged by pure linear
// 64KB copy (Vt is pre-transposed + pre-swizzled). Unnormalized p kept bf16
// in regs; MFMA; epilogue scales by 1/sum. Regular (L2) attn stores — NT
// stores measured -36us in R5 (bypasses L2 write combining).
// ---------------------------------------------------------------------------
__global__ __launch_bounds__(256) void fused_softmax_agg_kernel(
    const float* __restrict__ ssrc, const float* __restrict__ strg,
    const void* __restrict__ smask, const void* __restrict__ tmask,
    const int* __restrict__ flag_p, const unsigned short* __restrict__ Vt,
    float* __restrict__ attn, unsigned short* __restrict__ agg_bf) {
    const int blk = blockIdx.x;
    const int stile = blk & 15;
    const int h = (blk >> 4) & 7;
    const int b = blk >> 7;
    const int tid = threadIdx.x;
    const int lane = tid & 63;
    const int wave = tid >> 6;
    const int flag = *flag_p;

    __shared__ __align__(16) float s_sm[NT];
    __shared__ __align__(16) unsigned short vt[32 * 1024];
    __shared__ float s_inv[64];

    const unsigned short* vsrc = Vt + (size_t)(b * NHEADS + h) * 32768;
#pragma unroll
    for (int it = 0; it < 16; ++it) {
        const int off = (it * 256 + tid) * 8;
        *(ushort8*)&vt[off] = *(const ushort8*)&vsrc[off];
    }
    for (int t = tid; t < NT; t += 256) {
        const bool mv = flag ? (((const int*)tmask)[b * NT + t] != 0)
                             : (((const unsigned char*)tmask)[b * NT + t] != 0);
        s_sm[t] = mv ? strg[((size_t)b * NT + t) * NHEADS + h] : -1e30f;
    }
    __syncthreads();

    const int r = lane & 15;
    const int g = lane >> 4;
    const int srow = stile * 64 + wave * 16 + r;
    const float ss = ssrc[((size_t)b * NS + srow) * NHEADS + h];
    const bool rowv = flag ? (((const int*)smask)[b * NS + srow] != 0)
                           : (((const unsigned char*)smask)[b * NS + srow] != 0);
    const int sw = (r & 7) << 3;
    const unsigned short* vr0 = vt + r * 1024;
    const unsigned short* vr1 = vt + (r + 16) * 1024;

    short8 preg[32];
    f32x4 acc0 = {0.f, 0.f, 0.f, 0.f};
    f32x4 acc1 = {0.f, 0.f, 0.f, 0.f};
    float sum = 0.f;

#pragma unroll
    for (int c = 0; c < 32; ++c) {
        const int tb = c * 32 + g * 8;
        const float4 v0 = *(const float4*)&s_sm[tb];
        const float4 v1 = *(const float4*)&s_sm[tb + 4];
        const float vv[8] = {v0.x, v0.y, v0.z, v0.w, v1.x, v1.y, v1.z, v1.w};
        short8 pa;
#pragma unroll
        for (int e = 0; e < 8; ++e) {
            float v = ss + vv[e];
            v = (v >= 0.f) ? v : 0.2f * v;
            const float p = __expf(v);
            sum += p;
            pa[e] = (short)f2bf(p);
        }
        preg[c] = pa;
        const short8 b0 = *(const short8*)&vr0[tb ^ sw];
        const short8 b1 = *(const short8*)&vr1[tb ^ sw];
        acc0 = __builtin_amdgcn_mfma_f32_16x16x32_bf16(pa, b0, acc0, 0, 0, 0);
        acc1 = __builtin_amdgcn_mfma_f32_16x16x32_bf16(pa, b1, acc1, 0, 0, 0);
    }

    sum += __shfl_xor(sum, 16);
    sum += __shfl_xor(sum, 32);
    const float inv = (rowv && sum > 0.f) ? 1.f / sum : 0.f;
    if (g == 0) s_inv[wave * 16 + r] = inv;

    float* arow = attn + ((size_t)((b * NHEADS + h) * NS) + srow) * NT;
#pragma unroll
    for (int c = 0; c < 32; ++c) {
        const int tb = c * 32 + g * 8;
        float o[8];
#pragma unroll
        for (int e = 0; e < 8; ++e)
            o[e] = bf2f((unsigned short)preg[c][e]) * inv;
        const float4 o0 = {o[0], o[1], o[2], o[3]};
        const float4 o1 = {o[4], o[5], o[6], o[7]};
        *(float4*)(arow + tb) = o0;
        *(float4*)(arow + tb + 4) = o1;
    }

    __syncthreads();
    const int orow = stile * 64 + wave * 16 + g * 4;
    unsigned short* ab = agg_bf + ((size_t)b * NS + orow) * NE + h * DH + r;
#pragma unroll
    for (int j = 0; j < 4; ++j) {
        const float iv = s_inv[wave * 16 + g * 4 + j];
        ab[(size_t)j * NE] = f2bf(acc0[j] * iv);
        ab[(size_t)j * NE + 16] = f2bf(acc1[j] * iv);
    }
}

// ---------------------------------------------------------------------------
// Kernel D: out = agg_bf @ W_out (bf16 MFMA, f32 out).
// ---------------------------------------------------------------------------
__global__ __launch_bounds__(256) void gemm_out_kernel(
    const unsigned short* __restrict__ Xb, const unsigned short* __restrict__ Wt,
    float* __restrict__ Yf) {
    __shared__ __align__(16) unsigned short As[64 * NE];
    const int tid = threadIdx.x;
    const int lane = tid & 63;
    const int w = tid >> 6;
    const int row0 = blockIdx.x * 64;
    const int col0 = blockIdx.y * 128;

#pragma unroll
    for (int it = 0; it < 8; ++it) {
        const int gf = it * 256 + tid;
        const int row = gf >> 5, g3 = gf & 31;
        const ushort8 v = *(const ushort8*)&Xb[(size_t)(row0 + row) * NE + g3 * 8];
        *(ushort8*)&As[row * NE + ((g3 ^ (row & 7)) * 8)] = v;
    }
    __syncthreads();

    const int r = lane & 15, g = lane >> 4;
    short8 af[8];
#pragma unroll
    for (int kk = 0; kk < 8; ++kk)
        af[kk] = *(const short8*)&As[(w * 16 + r) * NE + (((kk * 4 + g) ^ (r & 7)) * 8)];

    f32x4 acc[8];
#pragma unroll
    for (int nt = 0; nt < 8; ++nt) acc[nt] = (f32x4){0.f, 0.f, 0.f, 0.f};
#pragma unroll
    for (int kk = 0; kk < 8; ++kk) {
#pragma unroll
        for (int nt = 0; nt < 8; ++nt) {
            const int col = col0 + nt * 16 + r;
            const short8 bf = *(const short8*)&Wt[(size_t)col * NE + kk * 32 + g * 8];
            acc[nt] = __builtin_amdgcn_mfma_f32_16x16x32_bf16(af[kk], bf, acc[nt], 0, 0, 0);
        }
    }

#pragma unroll
    for (int nt = 0; nt < 8; ++nt) {
        const int col = col0 + nt * 16 + r;
#pragma unroll
        for (int j = 0; j < 4; ++j) {
            const int row = row0 + w * 16 + g * 4 + j;
            Yf[(size_t)row * NE + col] = acc[nt][j];
        }
    }
}

extern "C" void kernel_launch(void* const* d_in, const int* in_sizes, int n_in,
                              void* d_out, int out_size, void* d_ws, size_t ws_size,
                              hipStream_t stream) {
    const float* src   = (const float*)d_in[0];
    const float* trg   = (const float*)d_in[1];
    const void*  smask = d_in[2];
    const void*  tmask = d_in[3];
    const float* Wsrc  = (const float*)d_in[4];
    const float* Wtrg  = (const float*)d_in[5];
    const float* asrc  = (const float*)d_in[6];
    const float* atrg  = (const float*)d_in[7];
    const float* Wout  = (const float*)d_in[8];

    float* out  = (float*)d_out;
    float* attn = out + (size_t)NB * NS * NE;

    char* wsb = (char*)d_ws;
    unsigned short* Vt     = (unsigned short*)(wsb + O_VT);
    unsigned short* agg_bf = (unsigned short*)(wsb + O_AGGB);
    unsigned short* Wt_t   = (unsigned short*)(wsb + O_WTT);
    unsigned short* Wt_o   = (unsigned short*)(wsb + O_WTO);
    float* c_src = (float*)(wsb + O_CSRC);
    float* c_trg = (float*)(wsb + O_CTRG);
    float* ssrc  = (float*)(wsb + O_SSRC);
    float* strg  = (float*)(wsb + O_STRG);
    int*   flag  = (int*)(wsb + O_FLAG);

    setup_kernel<<<35, 256, 0, stream>>>(
        (const unsigned*)tmask, Wsrc, Wtrg, Wout, asrc, atrg,
        c_src, c_trg, Wt_t, Wt_o, flag);

    mid_kernel<<<768, 256, 0, stream>>>(
        src, trg, c_src, c_trg, Wt_t, Vt, ssrc, strg);

    fused_softmax_agg_kernel<<<NB * NHEADS * (NS / 64), 256, 0, stream>>>(
        ssrc, strg, smask, tmask, flag, Vt, attn, agg_bf);

    gemm_out_kernel<<<dim3(128, 2), 256, 0, stream>>>(agg_bf, Wt_o, out);
}

// Round 7
// 104.429 us; speedup vs baseline: 1.6663x; 1.0749x over previous
//
#include <hip/hip_runtime.h>
#include <hip/hip_bf16.h>
#include <math.h>

#define NB 8
#define NS 1024
#define NT 1024
#define NE 256
#define NHEADS 8
#define DH 32

typedef __attribute__((ext_vector_type(8))) short short8;
typedef __attribute__((ext_vector_type(8))) unsigned short ushort8;
typedef __attribute__((ext_vector_type(4))) float f32x4;

// ws layout (byte offsets)
#define O_VT    0u                        // ushort[8][8][32][1024] V^T swizzled
#define O_AGGB  (4u<<20)                  // ushort[8192*256] agg bf16 [s][hd]
#define O_WTT   (8u<<20)                  // ushort[256*256] W_trg^T bf16 [n][k]
#define O_WTO   ((8u<<20)+131072u)        // ushort[256*256] W_out^T bf16 [n][k]
#define O_CSRC  ((8u<<20)+262144u)        // float[8*256]
#define O_CTRG  (O_CSRC+8192u)
#define O_SSRC  (O_CTRG+8192u)            // float[8192*8]
#define O_STRG  (O_SSRC+262144u)          // float[8192*8]
#define O_FLAG  (O_STRG+262144u)          // int

__device__ __forceinline__ unsigned short f2bf(float f) {
    __hip_bfloat16 h = __float2bfloat16(f);
    union { __hip_bfloat16 h; unsigned short u; } c; c.h = h;
    return c.u;
}
__device__ __forceinline__ float bf2f(unsigned short u) {
    union { unsigned u; float f; } x; x.u = ((unsigned)u) << 16;
    return x.f;
}

// ---------------------------------------------------------------------------
// Kernel A: bid0 = mask-layout probe; bid1/2 = c_src/c_trg (f32, exact);
// bid3..34 = W_trg/W_out 64x64 LDS-tile transposes -> bf16 [n][k], coalesced.
// ---------------------------------------------------------------------------
__global__ __launch_bounds__(256) void setup_kernel(
    const unsigned* __restrict__ tmask_dw, const float* __restrict__ Wsrc,
    const float* __restrict__ Wtrg, const float* __restrict__ Wout,
    const float* __restrict__ asrc, const float* __restrict__ atrg,
    float* __restrict__ c_src, float* __restrict__ c_trg,
    unsigned short* __restrict__ Wt_t, unsigned short* __restrict__ Wt_o,
    int* __restrict__ flag) {
    __shared__ __align__(16) char sm[16640];
    const int tid = threadIdx.x;
    const int bid = blockIdx.x;

    if (bid == 0) {
        __shared__ int s_ok;
        if (tid == 0) s_ok = 1;
        __syncthreads();
        for (int i = tid; i < 2048; i += 256)
            if (tmask_dw[i] > 1u) s_ok = 0;
        __syncthreads();
        if (tid == 0) *flag = s_ok;
    } else if (bid <= 2) {
        float* a_sh = (float*)sm;
        const float* W = (bid == 1) ? Wsrc : Wtrg;
        const float* a = (bid == 1) ? asrc : atrg;
        float* c = (bid == 1) ? c_src : c_trg;
        a_sh[tid] = a[tid];
        __syncthreads();
        const int e = tid;
        float ch[8];
#pragma unroll
        for (int h = 0; h < 8; ++h) ch[h] = 0.f;
        for (int i = 0; i < 64; ++i) {
            const float4 wv = *(const float4*)&W[(size_t)e * NE + i * 4];
            const int h = i >> 3, d0 = (i & 7) * 4;
            ch[h] += wv.x * a_sh[h * 32 + d0] + wv.y * a_sh[h * 32 + d0 + 1] +
                     wv.z * a_sh[h * 32 + d0 + 2] + wv.w * a_sh[h * 32 + d0 + 3];
        }
#pragma unroll
        for (int h = 0; h < 8; ++h) c[h * NE + e] = ch[h];
    } else {
        const int q = bid - 3;                    // 0..31
        const float* W = (q >> 4) ? Wout : Wtrg;
        unsigned short* Wt = (q >> 4) ? Wt_o : Wt_t;
        const int tl = q & 15;
        const int k0 = (tl >> 2) * 64, n0 = (tl & 3) * 64;
        float* xs = (float*)sm;                   // [64][65]
#pragma unroll
        for (int it = 0; it < 4; ++it) {
            const int slot = it * 256 + tid;      // 1024 float4 slots
            const int k = slot >> 4, c4 = slot & 15;
            const float4 v = *(const float4*)&W[(size_t)(k0 + k) * NE + n0 + c4 * 4];
            float* p = &xs[k * 65 + c4 * 4];
            p[0] = v.x; p[1] = v.y; p[2] = v.z; p[3] = v.w;
        }
        __syncthreads();
#pragma unroll
        for (int it = 0; it < 2; ++it) {
            const int slot = it * 256 + tid;      // 512 slots
            const int n = slot >> 3, kc = slot & 7;
            ushort8 v;
#pragma unroll
            for (int e = 0; e < 8; ++e)
                v[e] = f2bf(xs[(kc * 8 + e) * 65 + n]);
            *(ushort8*)&Wt[(size_t)(n0 + n) * NE + k0 + kc * 8] = v;
        }
    }
}

// ---------------------------------------------------------------------------
// Kernel B: bid<256 -> V gemm (trg @ W_trg, bf16 MFMA) with LDS-transpose
// epilogue writing V^T swizzled to global Vt[b][h][d][t^((d&7)<<3)];
// bid>=256 -> score rows (src@c_src / trg@c_trg), exact f32.
// ---------------------------------------------------------------------------
__global__ __launch_bounds__(256) void mid_kernel(
    const float* __restrict__ src, const float* __restrict__ trg,
    const float* __restrict__ c_src, const float* __restrict__ c_trg,
    const unsigned short* __restrict__ Wt_t, unsigned short* __restrict__ Vt,
    float* __restrict__ ssrc, float* __restrict__ strg) {
    __shared__ __align__(16) char sm[49152];
    const int tid = threadIdx.x;
    const int bid = blockIdx.x;

    if (bid < 256) {
        unsigned short* As = (unsigned short*)sm;            // [64][256]
        unsigned short* ldsT = (unsigned short*)(sm + 32768); // [128][64]
        const int lane = tid & 63, w = tid >> 6;
        const int row0 = (bid >> 1) * 64;
        const int col0 = (bid & 1) * 128;

#pragma unroll
        for (int it = 0; it < 8; ++it) {
            const int gf = it * 256 + tid;
            const int row = gf >> 5, g3 = gf & 31;
            const float4 a = *(const float4*)&trg[(size_t)(row0 + row) * NE + g3 * 8];
            const float4 b = *(const float4*)&trg[(size_t)(row0 + row) * NE + g3 * 8 + 4];
            ushort8 v;
            v[0] = f2bf(a.x); v[1] = f2bf(a.y); v[2] = f2bf(a.z); v[3] = f2bf(a.w);
            v[4] = f2bf(b.x); v[5] = f2bf(b.y); v[6] = f2bf(b.z); v[7] = f2bf(b.w);
            *(ushort8*)&As[row * NE + ((g3 ^ (row & 7)) * 8)] = v;
        }
        __syncthreads();

        const int r = lane & 15, g = lane >> 4;
        short8 af[8];
#pragma unroll
        for (int kk = 0; kk < 8; ++kk)
            af[kk] = *(const short8*)&As[(w * 16 + r) * NE + (((kk * 4 + g) ^ (r & 7)) * 8)];

        f32x4 acc[8];
#pragma unroll
        for (int nt = 0; nt < 8; ++nt) acc[nt] = (f32x4){0.f, 0.f, 0.f, 0.f};
#pragma unroll
        for (int kk = 0; kk < 8; ++kk) {
#pragma unroll
            for (int nt = 0; nt < 8; ++nt) {
                const int col = col0 + nt * 16 + r;
                const short8 bf = *(const short8*)&Wt_t[(size_t)col * NE + kk * 32 + g * 8];
                acc[nt] = __builtin_amdgcn_mfma_f32_16x16x32_bf16(af[kk], bf, acc[nt], 0, 0, 0);
            }
        }
        __syncthreads();   // As reads done; ldsT region reused below

        // transpose epilogue: ldsT[col][t ^ ((col&7)<<3)] = bf16(acc)
#pragma unroll
        for (int nt = 0; nt < 8; ++nt) {
            const int cl = nt * 16 + r;
            const int sw = (cl & 7) << 3;
#pragma unroll
            for (int j = 0; j < 4; ++j) {
                const int t = w * 16 + g * 4 + j;
                ldsT[cl * 64 + (t ^ sw)] = f2bf(acc[nt][j]);
            }
        }
        __syncthreads();

        const int b = row0 >> 10, t0 = row0 & 1023;
#pragma unroll
        for (int it = 0; it < 4; ++it) {
            const int slot = it * 256 + tid;      // 1024 chunks
            const int cl = slot >> 3, ch = slot & 7;
            const int colg = col0 + cl;
            const int h = colg >> 5, d = colg & 31;
            *(ushort8*)&Vt[(((size_t)(b * 8 + h)) * 32 + d) * 1024 + t0 + ch * 8] =
                *(const ushort8*)&ldsT[cl * 64 + ch * 8];
        }
    } else {
        float* xs = (float*)sm;                  // [32][256]
        float* cs = (float*)(sm + 32768);        // [8][256]
        const int rowg0 = (bid - 256) * 32;
        const bool is_src = rowg0 < NB * NS;
        const float* X = is_src ? (src + (size_t)rowg0 * NE)
                                : (trg + (size_t)(rowg0 - NB * NS) * NE);
        const float* C = is_src ? c_src : c_trg;
        float* S = is_src ? (ssrc + (size_t)rowg0 * NHEADS)
                          : (strg + (size_t)(rowg0 - NB * NS) * NHEADS);

#pragma unroll
        for (int it = 0; it < 8; ++it) {
            const int slot = it * 256 + tid;     // float4 slots
            const int row = slot >> 6, c4 = slot & 63;
            *(float4*)&xs[row * NE + c4 * 4] =
                *(const float4*)&X[(size_t)row * NE + c4 * 4];
            cs[slot] = C[slot];
        }
        __syncthreads();

        const int r = tid >> 3, h = tid & 7;
        float s = 0.f;
        for (int e = 0; e < NE; e += 4) {
            const float4 x = *(const float4*)&xs[r * NE + e];
            const float4 c = *(const float4*)&cs[h * NE + e];
            s += x.x * c.x + x.y * c.y + x.z * c.z + x.w * c.w;
        }
        S[(size_t)r * NHEADS + h] = s;
    }
}

// ---------------------------------------------------------------------------
// Kernel C: fused softmax + attn write + aggregation.
// High-occupancy version: no V LDS staging (B-frags read straight from
// global Vt, which is L2-resident at 4 MB total), no preg cache (2-pass
// exp recompute — exp is ~2 us chip-wide, 128 VGPRs were not worth it).
// LDS ~4.5 KB, VGPR ~80 -> ~6 blocks/CU, all 1024 blocks resident.
// ---------------------------------------------------------------------------
__global__ __launch_bounds__(256) void fused_softmax_agg_kernel(
    const float* __restrict__ ssrc, const float* __restrict__ strg,
    const void* __restrict__ smask, const void* __restrict__ tmask,
    const int* __restrict__ flag_p, const unsigned short* __restrict__ Vt,
    float* __restrict__ attn, unsigned short* __restrict__ agg_bf) {
    const int blk = blockIdx.x;
    const int stile = blk & 15;
    const int h = (blk >> 4) & 7;
    const int b = blk >> 7;
    const int tid = threadIdx.x;
    const int lane = tid & 63;
    const int wave = tid >> 6;
    const int flag = *flag_p;

    __shared__ __align__(16) float s_sm[NT];
    __shared__ float s_inv[64];

    for (int t = tid; t < NT; t += 256) {
        const bool mv = flag ? (((const int*)tmask)[b * NT + t] != 0)
                             : (((const unsigned char*)tmask)[b * NT + t] != 0);
        s_sm[t] = mv ? strg[((size_t)b * NT + t) * NHEADS + h] : -1e30f;
    }
    __syncthreads();

    const int r = lane & 15;
    const int g = lane >> 4;
    const int srow = stile * 64 + wave * 16 + r;
    const float ss = ssrc[((size_t)b * NS + srow) * NHEADS + h];
    const bool rowv = flag ? (((const int*)smask)[b * NS + srow] != 0)
                           : (((const unsigned char*)smask)[b * NS + srow] != 0);
    const int sw = (r & 7) << 3;
    const unsigned short* vr0 = Vt + (size_t)(b * NHEADS + h) * 32768 + r * 1024;
    const unsigned short* vr1 = vr0 + 16 * 1024;

    // pass 1: row sum of exp(leaky(score))
    float sum = 0.f;
#pragma unroll 4
    for (int c = 0; c < 32; ++c) {
        const int tb = c * 32 + g * 8;
        const float4 v0 = *(const float4*)&s_sm[tb];
        const float4 v1 = *(const float4*)&s_sm[tb + 4];
        const float vv[8] = {v0.x, v0.y, v0.z, v0.w, v1.x, v1.y, v1.z, v1.w};
#pragma unroll
        for (int e = 0; e < 8; ++e) {
            float v = ss + vv[e];
            v = (v >= 0.f) ? v : 0.2f * v;
            sum += __expf(v);
        }
    }
    sum += __shfl_xor(sum, 16);
    sum += __shfl_xor(sum, 32);
    const float inv = (rowv && sum > 0.f) ? 1.f / sum : 0.f;
    if (g == 0) s_inv[wave * 16 + r] = inv;

    // pass 2: p -> attn store (f32, full precision) + MFMA vs global Vt
    f32x4 acc0 = {0.f, 0.f, 0.f, 0.f};
    f32x4 acc1 = {0.f, 0.f, 0.f, 0.f};
    float* arow = attn + ((size_t)((b * NHEADS + h) * NS) + srow) * NT;

#pragma unroll 4
    for (int c = 0; c < 32; ++c) {
        const int tb = c * 32 + g * 8;
        const short8 b0 = *(const short8*)&vr0[tb ^ sw];
        const short8 b1 = *(const short8*)&vr1[tb ^ sw];
        const float4 v0 = *(const float4*)&s_sm[tb];
        const float4 v1 = *(const float4*)&s_sm[tb + 4];
        const float vv[8] = {v0.x, v0.y, v0.z, v0.w, v1.x, v1.y, v1.z, v1.w};
        float p[8];
        short8 pa;
#pragma unroll
        for (int e = 0; e < 8; ++e) {
            float v = ss + vv[e];
            v = (v >= 0.f) ? v : 0.2f * v;
            p[e] = __expf(v);
            pa[e] = (short)f2bf(p[e]);
        }
        const float4 o0 = {p[0] * inv, p[1] * inv, p[2] * inv, p[3] * inv};
        const float4 o1 = {p[4] * inv, p[5] * inv, p[6] * inv, p[7] * inv};
        *(float4*)(arow + tb) = o0;
        *(float4*)(arow + tb + 4) = o1;
        acc0 = __builtin_amdgcn_mfma_f32_16x16x32_bf16(pa, b0, acc0, 0, 0, 0);
        acc1 = __builtin_amdgcn_mfma_f32_16x16x32_bf16(pa, b1, acc1, 0, 0, 0);
    }

    __syncthreads();
    const int orow = stile * 64 + wave * 16 + g * 4;
    unsigned short* ab = agg_bf + ((size_t)b * NS + orow) * NE + h * DH + r;
#pragma unroll
    for (int j = 0; j < 4; ++j) {
        const float iv = s_inv[wave * 16 + g * 4 + j];
        ab[(size_t)j * NE] = f2bf(acc0[j] * iv);
        ab[(size_t)j * NE + 16] = f2bf(acc1[j] * iv);
    }
}

// ---------------------------------------------------------------------------
// Kernel D: out = agg_bf @ W_out (bf16 MFMA, f32 out).
// ---------------------------------------------------------------------------
__global__ __launch_bounds__(256) void gemm_out_kernel(
    const unsigned short* __restrict__ Xb, const unsigned short* __restrict__ Wt,
    float* __restrict__ Yf) {
    __shared__ __align__(16) unsigned short As[64 * NE];
    const int tid = threadIdx.x;
    const int lane = tid & 63;
    const int w = tid >> 6;
    const int row0 = blockIdx.x * 64;
    const int col0 = blockIdx.y * 128;

#pragma unroll
    for (int it = 0; it < 8; ++it) {
        const int gf = it * 256 + tid;
        const int row = gf >> 5, g3 = gf & 31;
        const ushort8 v = *(const ushort8*)&Xb[(size_t)(row0 + row) * NE + g3 * 8];
        *(ushort8*)&As[row * NE + ((g3 ^ (row & 7)) * 8)] = v;
    }
    __syncthreads();

    const int r = lane & 15, g = lane >> 4;
    short8 af[8];
#pragma unroll
    for (int kk = 0; kk < 8; ++kk)
        af[kk] = *(const short8*)&As[(w * 16 + r) * NE + (((kk * 4 + g) ^ (r & 7)) * 8)];

    f32x4 acc[8];
#pragma unroll
    for (int nt = 0; nt < 8; ++nt) acc[nt] = (f32x4){0.f, 0.f, 0.f, 0.f};
#pragma unroll
    for (int kk = 0; kk < 8; ++kk) {
#pragma unroll
        for (int nt = 0; nt < 8; ++nt) {
            const int col = col0 + nt * 16 + r;
            const short8 bf = *(const short8*)&Wt[(size_t)col * NE + kk * 32 + g * 8];
            acc[nt] = __builtin_amdgcn_mfma_f32_16x16x32_bf16(af[kk], bf, acc[nt], 0, 0, 0);
        }
    }

#pragma unroll
    for (int nt = 0; nt < 8; ++nt) {
        const int col = col0 + nt * 16 + r;
#pragma unroll
        for (int j = 0; j < 4; ++j) {
            const int row = row0 + w * 16 + g * 4 + j;
            Yf[(size_t)row * NE + col] = acc[nt][j];
        }
    }
}

extern "C" void kernel_launch(void* const* d_in, const int* in_sizes, int n_in,
                              void* d_out, int out_size, void* d_ws, size_t ws_size,
                              hipStream_t stream) {
    const float* src   = (const float*)d_in[0];
    const float* trg   = (const float*)d_in[1];
    const void*  smask = d_in[2];
    const void*  tmask = d_in[3];
    const float* Wsrc  = (const float*)d_in[4];
    const float* Wtrg  = (const float*)d_in[5];
    const float* asrc  = (const float*)d_in[6];
    const float* atrg  = (const float*)d_in[7];
    const float* Wout  = (const float*)d_in[8];

    float* out  = (float*)d_out;
    float* attn = out + (size_t)NB * NS * NE;

    char* wsb = (char*)d_ws;
    unsigned short* Vt     = (unsigned short*)(wsb + O_VT);
    unsigned short* agg_bf = (unsigned short*)(wsb + O_AGGB);
    unsigned short* Wt_t   = (unsigned short*)(wsb + O_WTT);
    unsigned short* Wt_o   = (unsigned short*)(wsb + O_WTO);
    float* c_src = (float*)(wsb + O_CSRC);
    float* c_trg = (float*)(wsb + O_CTRG);
    float* ssrc  = (float*)(wsb + O_SSRC);
    float* strg  = (float*)(wsb + O_STRG);
    int*   flag  = (int*)(wsb + O_FLAG);

    setup_kernel<<<35, 256, 0, stream>>>(
        (const unsigned*)tmask, Wsrc, Wtrg, Wout, asrc, atrg,
        c_src, c_trg, Wt_t, Wt_o, flag);

    mid_kernel<<<768, 256, 0, stream>>>(
        src, trg, c_src, c_trg, Wt_t, Vt, ssrc, strg);

    fused_softmax_agg_kernel<<<NB * NHEADS * (NS / 64), 256, 0, stream>>>(
        ssrc, strg, smask, tmask, flag, Vt, attn, agg_bf);

    gemm_out_kernel<<<dim3(128, 2), 256, 0, stream>>>(agg_bf, Wt_o, out);
}

// Round 8
// 98.492 us; speedup vs baseline: 1.7667x; 1.0603x over previous
//
#include <hip/hip_runtime.h>
#include <hip/hip_bf16.h>
#include <math.h>

#define NB 8
#define NS 1024
#define NT 1024
#define NE 256
#define NHEADS 8
#define DH 32

typedef __attribute__((ext_vector_type(8))) short short8;
typedef __attribute__((ext_vector_type(8))) unsigned short ushort8;
typedef __attribute__((ext_vector_type(4))) float f32x4;

// ws layout (byte offsets)
#define O_VT    0u                        // ushort[8][8][32][1024] V^T swizzled
#define O_AGGB  (4u<<20)                  // ushort[8192*256] agg bf16 [s][hd]
#define O_WTT   (8u<<20)                  // ushort[256*256] W_trg^T bf16 [n][k]
#define O_WTO   ((8u<<20)+131072u)        // ushort[256*256] W_out^T bf16 [n][k]
#define O_CSRC  ((8u<<20)+262144u)        // float[8*256]
#define O_CTRG  (O_CSRC+8192u)
#define O_SSRC  (O_CTRG+8192u)            // float[8192*8]
#define O_STRG  (O_SSRC+262144u)          // float[8192*8]
#define O_FLAG  (O_STRG+262144u)          // int

__device__ __forceinline__ unsigned short f2bf(float f) {
    __hip_bfloat16 h = __float2bfloat16(f);
    union { __hip_bfloat16 h; unsigned short u; } c; c.h = h;
    return c.u;
}
__device__ __forceinline__ float bf2f(unsigned short u) {
    union { unsigned u; float f; } x; x.u = ((unsigned)u) << 16;
    return x.f;
}
__device__ __forceinline__ float leaky(float v) {
    return (v >= 0.f) ? v : 0.2f * v;
}

// ---------------------------------------------------------------------------
// Kernel A: bid0 = mask-layout probe; bid1/2 = c_src/c_trg (f32, exact);
// bid3..34 = W_trg/W_out 64x64 LDS-tile transposes -> bf16 [n][k], coalesced.
// ---------------------------------------------------------------------------
__global__ __launch_bounds__(256) void setup_kernel(
    const unsigned* __restrict__ tmask_dw, const float* __restrict__ Wsrc,
    const float* __restrict__ Wtrg, const float* __restrict__ Wout,
    const float* __restrict__ asrc, const float* __restrict__ atrg,
    float* __restrict__ c_src, float* __restrict__ c_trg,
    unsigned short* __restrict__ Wt_t, unsigned short* __restrict__ Wt_o,
    int* __restrict__ flag) {
    __shared__ __align__(16) char sm[16640];
    const int tid = threadIdx.x;
    const int bid = blockIdx.x;

    if (bid == 0) {
        __shared__ int s_ok;
        if (tid == 0) s_ok = 1;
        __syncthreads();
        for (int i = tid; i < 2048; i += 256)
            if (tmask_dw[i] > 1u) s_ok = 0;
        __syncthreads();
        if (tid == 0) *flag = s_ok;
    } else if (bid <= 2) {
        float* a_sh = (float*)sm;
        const float* W = (bid == 1) ? Wsrc : Wtrg;
        const float* a = (bid == 1) ? asrc : atrg;
        float* c = (bid == 1) ? c_src : c_trg;
        a_sh[tid] = a[tid];
        __syncthreads();
        const int e = tid;
        float ch[8];
#pragma unroll
        for (int h = 0; h < 8; ++h) ch[h] = 0.f;
        for (int i = 0; i < 64; ++i) {
            const float4 wv = *(const float4*)&W[(size_t)e * NE + i * 4];
            const int h = i >> 3, d0 = (i & 7) * 4;
            ch[h] += wv.x * a_sh[h * 32 + d0] + wv.y * a_sh[h * 32 + d0 + 1] +
                     wv.z * a_sh[h * 32 + d0 + 2] + wv.w * a_sh[h * 32 + d0 + 3];
        }
#pragma unroll
        for (int h = 0; h < 8; ++h) c[h * NE + e] = ch[h];
    } else {
        const int q = bid - 3;                    // 0..31
        const float* W = (q >> 4) ? Wout : Wtrg;
        unsigned short* Wt = (q >> 4) ? Wt_o : Wt_t;
        const int tl = q & 15;
        const int k0 = (tl >> 2) * 64, n0 = (tl & 3) * 64;
        float* xs = (float*)sm;                   // [64][65]
#pragma unroll
        for (int it = 0; it < 4; ++it) {
            const int slot = it * 256 + tid;      // 1024 float4 slots
            const int k = slot >> 4, c4 = slot & 15;
            const float4 v = *(const float4*)&W[(size_t)(k0 + k) * NE + n0 + c4 * 4];
            float* p = &xs[k * 65 + c4 * 4];
            p[0] = v.x; p[1] = v.y; p[2] = v.z; p[3] = v.w;
        }
        __syncthreads();
#pragma unroll
        for (int it = 0; it < 2; ++it) {
            const int slot = it * 256 + tid;      // 512 slots
            const int n = slot >> 3, kc = slot & 7;
            ushort8 v;
#pragma unroll
            for (int e = 0; e < 8; ++e)
                v[e] = f2bf(xs[(kc * 8 + e) * 65 + n]);
            *(ushort8*)&Wt[(size_t)(n0 + n) * NE + k0 + kc * 8] = v;
        }
    }
}

// ---------------------------------------------------------------------------
// Kernel B: bid<256 -> V gemm (trg @ W_trg, bf16 MFMA) with LDS-transpose
// epilogue writing V^T swizzled to global Vt[b][h][d][t^((d&7)<<3)];
// bid>=256 -> score rows (src@c_src / trg@c_trg), exact f32.
// ---------------------------------------------------------------------------
__global__ __launch_bounds__(256) void mid_kernel(
    const float* __restrict__ src, const float* __restrict__ trg,
    const float* __restrict__ c_src, const float* __restrict__ c_trg,
    const unsigned short* __restrict__ Wt_t, unsigned short* __restrict__ Vt,
    float* __restrict__ ssrc, float* __restrict__ strg) {
    __shared__ __align__(16) char sm[49152];
    const int tid = threadIdx.x;
    const int bid = blockIdx.x;

    if (bid < 256) {
        unsigned short* As = (unsigned short*)sm;            // [64][256]
        unsigned short* ldsT = (unsigned short*)(sm + 32768); // [128][64]
        const int lane = tid & 63, w = tid >> 6;
        const int row0 = (bid >> 1) * 64;
        const int col0 = (bid & 1) * 128;

#pragma unroll
        for (int it = 0; it < 8; ++it) {
            const int gf = it * 256 + tid;
            const int row = gf >> 5, g3 = gf & 31;
            const float4 a = *(const float4*)&trg[(size_t)(row0 + row) * NE + g3 * 8];
            const float4 b = *(const float4*)&trg[(size_t)(row0 + row) * NE + g3 * 8 + 4];
            ushort8 v;
            v[0] = f2bf(a.x); v[1] = f2bf(a.y); v[2] = f2bf(a.z); v[3] = f2bf(a.w);
            v[4] = f2bf(b.x); v[5] = f2bf(b.y); v[6] = f2bf(b.z); v[7] = f2bf(b.w);
            *(ushort8*)&As[row * NE + ((g3 ^ (row & 7)) * 8)] = v;
        }
        __syncthreads();

        const int r = lane & 15, g = lane >> 4;
        short8 af[8];
#pragma unroll
        for (int kk = 0; kk < 8; ++kk)
            af[kk] = *(const short8*)&As[(w * 16 + r) * NE + (((kk * 4 + g) ^ (r & 7)) * 8)];

        f32x4 acc[8];
#pragma unroll
        for (int nt = 0; nt < 8; ++nt) acc[nt] = (f32x4){0.f, 0.f, 0.f, 0.f};
#pragma unroll
        for (int kk = 0; kk < 8; ++kk) {
#pragma unroll
            for (int nt = 0; nt < 8; ++nt) {
                const int col = col0 + nt * 16 + r;
                const short8 bf = *(const short8*)&Wt_t[(size_t)col * NE + kk * 32 + g * 8];
                acc[nt] = __builtin_amdgcn_mfma_f32_16x16x32_bf16(af[kk], bf, acc[nt], 0, 0, 0);
            }
        }
        __syncthreads();   // As reads done; ldsT region reused below

        // transpose epilogue: ldsT[col][t ^ ((col&7)<<3)] = bf16(acc)
#pragma unroll
        for (int nt = 0; nt < 8; ++nt) {
            const int cl = nt * 16 + r;
            const int sw = (cl & 7) << 3;
#pragma unroll
            for (int j = 0; j < 4; ++j) {
                const int t = w * 16 + g * 4 + j;
                ldsT[cl * 64 + (t ^ sw)] = f2bf(acc[nt][j]);
            }
        }
        __syncthreads();

        const int b = row0 >> 10, t0 = row0 & 1023;
#pragma unroll
        for (int it = 0; it < 4; ++it) {
            const int slot = it * 256 + tid;      // 1024 chunks
            const int cl = slot >> 3, ch = slot & 7;
            const int colg = col0 + cl;
            const int h = colg >> 5, d = colg & 31;
            *(ushort8*)&Vt[(((size_t)(b * 8 + h)) * 32 + d) * 1024 + t0 + ch * 8] =
                *(const ushort8*)&ldsT[cl * 64 + ch * 8];
        }
    } else {
        float* xs = (float*)sm;                  // [32][256]
        float* cs = (float*)(sm + 32768);        // [8][256]
        const int rowg0 = (bid - 256) * 32;
        const bool is_src = rowg0 < NB * NS;
        const float* X = is_src ? (src + (size_t)rowg0 * NE)
                                : (trg + (size_t)(rowg0 - NB * NS) * NE);
        const float* C = is_src ? c_src : c_trg;
        float* S = is_src ? (ssrc + (size_t)rowg0 * NHEADS)
                          : (strg + (size_t)(rowg0 - NB * NS) * NHEADS);

#pragma unroll
        for (int it = 0; it < 8; ++it) {
            const int slot = it * 256 + tid;     // float4 slots
            const int row = slot >> 6, c4 = slot & 63;
            *(float4*)&xs[row * NE + c4 * 4] =
                *(const float4*)&X[(size_t)row * NE + c4 * 4];
            cs[slot] = C[slot];
        }
        __syncthreads();

        const int r = tid >> 3, h = tid & 7;
        float s = 0.f;
        for (int e = 0; e < NE; e += 4) {
            const float4 x = *(const float4*)&xs[r * NE + e];
            const float4 c = *(const float4*)&cs[h * NE + e];
            s += x.x * c.x + x.y * c.y + x.z * c.z + x.w * c.w;
        }
        S[(size_t)r * NHEADS + h] = s;
    }
}

// ---------------------------------------------------------------------------
// Kernel C: fused softmax + attn write + aggregation.
// passA (MFMA A-layout): exp -> bf16, UNNORMALIZED MFMA accumulate + row sum
//   (epilogue rescales by 1/sum). No stores.
// passB (linear layout, after barrier): each wave walks its 16 rows
//   contiguously; each store inst = 1KB contiguous (8 line segments vs 16
//   for the A-layout store — TA-divergence halved, sequential row writes).
// ---------------------------------------------------------------------------
__global__ __launch_bounds__(256) void fused_softmax_agg_kernel(
    const float* __restrict__ ssrc, const float* __restrict__ strg,
    const void* __restrict__ smask, const void* __restrict__ tmask,
    const int* __restrict__ flag_p, const unsigned short* __restrict__ Vt,
    float* __restrict__ attn, unsigned short* __restrict__ agg_bf) {
    const int blk = blockIdx.x;
    const int stile = blk & 15;
    const int h = (blk >> 4) & 7;
    const int b = blk >> 7;
    const int tid = threadIdx.x;
    const int lane = tid & 63;
    const int wave = tid >> 6;
    const int flag = *flag_p;

    __shared__ __align__(16) float s_sm[NT];
    __shared__ float s_inv[64];
    __shared__ float s_ss[64];

    for (int t = tid; t < NT; t += 256) {
        const bool mv = flag ? (((const int*)tmask)[b * NT + t] != 0)
                             : (((const unsigned char*)tmask)[b * NT + t] != 0);
        s_sm[t] = mv ? strg[((size_t)b * NT + t) * NHEADS + h] : -1e30f;
    }
    __syncthreads();

    const int r = lane & 15;
    const int g = lane >> 4;
    const int srow = stile * 64 + wave * 16 + r;
    const float ss = ssrc[((size_t)b * NS + srow) * NHEADS + h];
    const bool rowv = flag ? (((const int*)smask)[b * NS + srow] != 0)
                           : (((const unsigned char*)smask)[b * NS + srow] != 0);
    const int sw = (r & 7) << 3;
    const unsigned short* vr0 = Vt + (size_t)(b * NHEADS + h) * 32768 + r * 1024;
    const unsigned short* vr1 = vr0 + 16 * 1024;

    // passA: unnormalized p (A-layout) -> row sum + MFMA
    f32x4 acc0 = {0.f, 0.f, 0.f, 0.f};
    f32x4 acc1 = {0.f, 0.f, 0.f, 0.f};
    float sum = 0.f;
#pragma unroll 4
    for (int c = 0; c < 32; ++c) {
        const int tb = c * 32 + g * 8;
        const short8 b0 = *(const short8*)&vr0[tb ^ sw];
        const short8 b1 = *(const short8*)&vr1[tb ^ sw];
        const float4 v0 = *(const float4*)&s_sm[tb];
        const float4 v1 = *(const float4*)&s_sm[tb + 4];
        const float vv[8] = {v0.x, v0.y, v0.z, v0.w, v1.x, v1.y, v1.z, v1.w};
        short8 pa;
#pragma unroll
        for (int e = 0; e < 8; ++e) {
            const float p = __expf(leaky(ss + vv[e]));
            sum += p;
            pa[e] = (short)f2bf(p);
        }
        acc0 = __builtin_amdgcn_mfma_f32_16x16x32_bf16(pa, b0, acc0, 0, 0, 0);
        acc1 = __builtin_amdgcn_mfma_f32_16x16x32_bf16(pa, b1, acc1, 0, 0, 0);
    }

    sum += __shfl_xor(sum, 16);
    sum += __shfl_xor(sum, 32);
    const float inv = (rowv && sum > 0.f) ? 1.f / sum : 0.f;
    if (g == 0) {
        s_inv[wave * 16 + r] = inv;
        s_ss[wave * 16 + r] = ss;
    }
    __syncthreads();

    // agg epilogue (C layout col=lane&15, row=(lane>>4)*4+reg), rescaled
    {
        const int orow = stile * 64 + wave * 16 + g * 4;
        unsigned short* ab = agg_bf + ((size_t)b * NS + orow) * NE + h * DH + r;
#pragma unroll
        for (int j = 0; j < 4; ++j) {
            const float iv = s_inv[wave * 16 + g * 4 + j];
            ab[(size_t)j * NE] = f2bf(acc0[j] * iv);
            ab[(size_t)j * NE + 16] = f2bf(acc1[j] * iv);
        }
    }

    // passB: coalesced attn stores — wave walks its 16 rows sequentially
    float* wbase = attn + ((size_t)((b * NHEADS + h) * NS) + stile * 64 + wave * 16) * NT;
    const float* ssv = &s_ss[wave * 16];
    const float* invv = &s_inv[wave * 16];
    for (int rr = 0; rr < 16; ++rr) {
        const float ssr = ssv[rr];
        const float ivr = invv[rr];
        float* arow = wbase + (size_t)rr * NT;
#pragma unroll
        for (int q = 0; q < 4; ++q) {
            const int t0 = q * 256 + lane * 4;
            const float4 sm4 = *(const float4*)&s_sm[t0];
            float4 o;
            o.x = __expf(leaky(ssr + sm4.x)) * ivr;
            o.y = __expf(leaky(ssr + sm4.y)) * ivr;
            o.z = __expf(leaky(ssr + sm4.z)) * ivr;
            o.w = __expf(leaky(ssr + sm4.w)) * ivr;
            *(float4*)&arow[t0] = o;
        }
    }
}

// ---------------------------------------------------------------------------
// Kernel D: out = agg_bf @ W_out (bf16 MFMA, f32 out).
// ---------------------------------------------------------------------------
__global__ __launch_bounds__(256) void gemm_out_kernel(
    const unsigned short* __restrict__ Xb, const unsigned short* __restrict__ Wt,
    float* __restrict__ Yf) {
    __shared__ __align__(16) unsigned short As[64 * NE];
    const int tid = threadIdx.x;
    const int lane = tid & 63;
    const int w = tid >> 6;
    const int row0 = blockIdx.x * 64;
    const int col0 = blockIdx.y * 128;

#pragma unroll
    for (int it = 0; it < 8; ++it) {
        const int gf = it * 256 + tid;
        const int row = gf >> 5, g3 = gf & 31;
        const ushort8 v = *(const ushort8*)&Xb[(size_t)(row0 + row) * NE + g3 * 8];
        *(ushort8*)&As[row * NE + ((g3 ^ (row & 7)) * 8)] = v;
    }
    __syncthreads();

    const int r = lane & 15, g = lane >> 4;
    short8 af[8];
#pragma unroll
    for (int kk = 0; kk < 8; ++kk)
        af[kk] = *(const short8*)&As[(w * 16 + r) * NE + (((kk * 4 + g) ^ (r & 7)) * 8)];

    f32x4 acc[8];
#pragma unroll
    for (int nt = 0; nt < 8; ++nt) acc[nt] = (f32x4){0.f, 0.f, 0.f, 0.f};
#pragma unroll
    for (int kk = 0; kk < 8; ++kk) {
#pragma unroll
        for (int nt = 0; nt < 8; ++nt) {
            const int col = col0 + nt * 16 + r;
            const short8 bf = *(const short8*)&Wt[(size_t)col * NE + kk * 32 + g * 8];
            acc[nt] = __builtin_amdgcn_mfma_f32_16x16x32_bf16(af[kk], bf, acc[nt], 0, 0, 0);
        }
    }

#pragma unroll
    for (int nt = 0; nt < 8; ++nt) {
        const int col = col0 + nt * 16 + r;
#pragma unroll
        for (int j = 0; j < 4; ++j) {
            const int row = row0 + w * 16 + g * 4 + j;
            Yf[(size_t)row * NE + col] = acc[nt][j];
        }
    }
}

extern "C" void kernel_launch(void* const* d_in, const int* in_sizes, int n_in,
                              void* d_out, int out_size, void* d_ws, size_t ws_size,
                              hipStream_t stream) {
    const float* src   = (const float*)d_in[0];
    const float* trg   = (const float*)d_in[1];
    const void*  smask = d_in[2];
    const void*  tmask = d_in[3];
    const float* Wsrc  = (const float*)d_in[4];
    const float* Wtrg  = (const float*)d_in[5];
    const float* asrc  = (const float*)d_in[6];
    const float* atrg  = (const float*)d_in[7];
    const float* Wout  = (const float*)d_in[8];

    float* out  = (float*)d_out;
    float* attn = out + (size_t)NB * NS * NE;

    char* wsb = (char*)d_ws;
    unsigned short* Vt     = (unsigned short*)(wsb + O_VT);
    unsigned short* agg_bf = (unsigned short*)(wsb + O_AGGB);
    unsigned short* Wt_t   = (unsigned short*)(wsb + O_WTT);
    unsigned short* Wt_o   = (unsigned short*)(wsb + O_WTO);
    float* c_src = (float*)(wsb + O_CSRC);
    float* c_trg = (float*)(wsb + O_CTRG);
    float* ssrc  = (float*)(wsb + O_SSRC);
    float* strg  = (float*)(wsb + O_STRG);
    int*   flag  = (int*)(wsb + O_FLAG);

    setup_kernel<<<35, 256, 0, stream>>>(
        (const unsigned*)tmask, Wsrc, Wtrg, Wout, asrc, atrg,
        c_src, c_trg, Wt_t, Wt_o, flag);

    mid_kernel<<<768, 256, 0, stream>>>(
        src, trg, c_src, c_trg, Wt_t, Vt, ssrc, strg);

    fused_softmax_agg_kernel<<<NB * NHEADS * (NS / 64), 256, 0, stream>>>(
        ssrc, strg, smask, tmask, flag, Vt, attn, agg_bf);

    gemm_out_kernel<<<dim3(128, 2), 256, 0, stream>>>(agg_bf, Wt_o, out);
}

// Round 9
// 98.165 us; speedup vs baseline: 1.7726x; 1.0033x over previous
//
#include <hip/hip_runtime.h>
#include <hip/hip_bf16.h>
#include <math.h>

#define NB 8
#define NS 1024
#define NT 1024
#define NE 256
#define NHEADS 8
#define DH 32
#define LOG2E 1.4426950408889634f

typedef __attribute__((ext_vector_type(8))) short short8;
typedef __attribute__((ext_vector_type(8))) unsigned short ushort8;
typedef __attribute__((ext_vector_type(4))) float f32x4;

// ws layout (byte offsets)
#define O_VT    0u                        // ushort[8][8][32][1024] V^T swizzled
#define O_WTT   (8u<<20)                  // ushort[256*256] W_trg^T bf16 [n][k]
#define O_WTO   ((8u<<20)+131072u)        // ushort[256*256] W_out^T bf16 [n][k]
#define O_CSRC  ((8u<<20)+262144u)        // float[8*256]
#define O_CTRG  (O_CSRC+8192u)
#define O_SSRC  (O_CTRG+8192u)            // float[8192*8]
#define O_STRG  (O_SSRC+262144u)          // float[8192*8]
#define O_FLAG  (O_STRG+262144u)          // int

__device__ __forceinline__ unsigned short f2bf(float f) {
    __hip_bfloat16 h = __float2bfloat16(f);
    union { __hip_bfloat16 h; unsigned short u; } c; c.h = h;
    return c.u;
}
__device__ __forceinline__ float leaky(float v) {
    return (v >= 0.f) ? v : 0.2f * v;
}
// raw v_exp_f32 (= exp2). Inputs are pre-scaled by LOG2E.
__device__ __forceinline__ float exp2_fast(float x) {
    float r;
    asm("v_exp_f32 %0, %1" : "=v"(r) : "v"(x));
    return r;
}

// ---------------------------------------------------------------------------
// Kernel A: bid0 = mask-layout probe; bid1/2 = c_src/c_trg (f32, exact);
// bid3..34 = W_trg/W_out 64x64 LDS-tile transposes -> bf16 [n][k], coalesced.
// ---------------------------------------------------------------------------
__global__ __launch_bounds__(256) void setup_kernel(
    const unsigned* __restrict__ tmask_dw, const float* __restrict__ Wsrc,
    const float* __restrict__ Wtrg, const float* __restrict__ Wout,
    const float* __restrict__ asrc, const float* __restrict__ atrg,
    float* __restrict__ c_src, float* __restrict__ c_trg,
    unsigned short* __restrict__ Wt_t, unsigned short* __restrict__ Wt_o,
    int* __restrict__ flag) {
    __shared__ __align__(16) char sm[16640];
    const int tid = threadIdx.x;
    const int bid = blockIdx.x;

    if (bid == 0) {
        __shared__ int s_ok;
        if (tid == 0) s_ok = 1;
        __syncthreads();
        for (int i = tid; i < 2048; i += 256)
            if (tmask_dw[i] > 1u) s_ok = 0;
        __syncthreads();
        if (tid == 0) *flag = s_ok;
    } else if (bid <= 2) {
        float* a_sh = (float*)sm;
        const float* W = (bid == 1) ? Wsrc : Wtrg;
        const float* a = (bid == 1) ? asrc : atrg;
        float* c = (bid == 1) ? c_src : c_trg;
        a_sh[tid] = a[tid];
        __syncthreads();
        const int e = tid;
        float ch[8];
#pragma unroll
        for (int h = 0; h < 8; ++h) ch[h] = 0.f;
        for (int i = 0; i < 64; ++i) {
            const float4 wv = *(const float4*)&W[(size_t)e * NE + i * 4];
            const int h = i >> 3, d0 = (i & 7) * 4;
            ch[h] += wv.x * a_sh[h * 32 + d0] + wv.y * a_sh[h * 32 + d0 + 1] +
                     wv.z * a_sh[h * 32 + d0 + 2] + wv.w * a_sh[h * 32 + d0 + 3];
        }
#pragma unroll
        for (int h = 0; h < 8; ++h) c[h * NE + e] = ch[h];
    } else {
        const int q = bid - 3;                    // 0..31
        const float* W = (q >> 4) ? Wout : Wtrg;
        unsigned short* Wt = (q >> 4) ? Wt_o : Wt_t;
        const int tl = q & 15;
        const int k0 = (tl >> 2) * 64, n0 = (tl & 3) * 64;
        float* xs = (float*)sm;                   // [64][65]
#pragma unroll
        for (int it = 0; it < 4; ++it) {
            const int slot = it * 256 + tid;      // 1024 float4 slots
            const int k = slot >> 4, c4 = slot & 15;
            const float4 v = *(const float4*)&W[(size_t)(k0 + k) * NE + n0 + c4 * 4];
            float* p = &xs[k * 65 + c4 * 4];
            p[0] = v.x; p[1] = v.y; p[2] = v.z; p[3] = v.w;
        }
        __syncthreads();
#pragma unroll
        for (int it = 0; it < 2; ++it) {
            const int slot = it * 256 + tid;      // 512 slots
            const int n = slot >> 3, kc = slot & 7;
            ushort8 v;
#pragma unroll
            for (int e = 0; e < 8; ++e)
                v[e] = f2bf(xs[(kc * 8 + e) * 65 + n]);
            *(ushort8*)&Wt[(size_t)(n0 + n) * NE + k0 + kc * 8] = v;
        }
    }
}

// ---------------------------------------------------------------------------
// Kernel B: bid<256 -> V gemm (trg @ W_trg, bf16 MFMA) with LDS-transpose
// epilogue writing V^T swizzled to global Vt[b][h][d][t^((d&7)<<3)];
// bid>=256 -> score rows (src@c_src / trg@c_trg), exact f32.
// ---------------------------------------------------------------------------
__global__ __launch_bounds__(256) void mid_kernel(
    const float* __restrict__ src, const float* __restrict__ trg,
    const float* __restrict__ c_src, const float* __restrict__ c_trg,
    const unsigned short* __restrict__ Wt_t, unsigned short* __restrict__ Vt,
    float* __restrict__ ssrc, float* __restrict__ strg) {
    __shared__ __align__(16) char sm[49152];
    const int tid = threadIdx.x;
    const int bid = blockIdx.x;

    if (bid < 256) {
        unsigned short* As = (unsigned short*)sm;            // [64][256]
        unsigned short* ldsT = (unsigned short*)(sm + 32768); // [128][64]
        const int lane = tid & 63, w = tid >> 6;
        const int row0 = (bid >> 1) * 64;
        const int col0 = (bid & 1) * 128;

#pragma unroll
        for (int it = 0; it < 8; ++it) {
            const int gf = it * 256 + tid;
            const int row = gf >> 5, g3 = gf & 31;
            const float4 a = *(const float4*)&trg[(size_t)(row0 + row) * NE + g3 * 8];
            const float4 b = *(const float4*)&trg[(size_t)(row0 + row) * NE + g3 * 8 + 4];
            ushort8 v;
            v[0] = f2bf(a.x); v[1] = f2bf(a.y); v[2] = f2bf(a.z); v[3] = f2bf(a.w);
            v[4] = f2bf(b.x); v[5] = f2bf(b.y); v[6] = f2bf(b.z); v[7] = f2bf(b.w);
            *(ushort8*)&As[row * NE + ((g3 ^ (row & 7)) * 8)] = v;
        }
        __syncthreads();

        const int r = lane & 15, g = lane >> 4;
        short8 af[8];
#pragma unroll
        for (int kk = 0; kk < 8; ++kk)
            af[kk] = *(const short8*)&As[(w * 16 + r) * NE + (((kk * 4 + g) ^ (r & 7)) * 8)];

        f32x4 acc[8];
#pragma unroll
        for (int nt = 0; nt < 8; ++nt) acc[nt] = (f32x4){0.f, 0.f, 0.f, 0.f};
#pragma unroll
        for (int kk = 0; kk < 8; ++kk) {
#pragma unroll
            for (int nt = 0; nt < 8; ++nt) {
                const int col = col0 + nt * 16 + r;
                const short8 bf = *(const short8*)&Wt_t[(size_t)col * NE + kk * 32 + g * 8];
                acc[nt] = __builtin_amdgcn_mfma_f32_16x16x32_bf16(af[kk], bf, acc[nt], 0, 0, 0);
            }
        }
        __syncthreads();   // As reads done; ldsT region reused below

        // transpose epilogue: ldsT[col][t ^ ((col&7)<<3)] = bf16(acc)
#pragma unroll
        for (int nt = 0; nt < 8; ++nt) {
            const int cl = nt * 16 + r;
            const int sw = (cl & 7) << 3;
#pragma unroll
            for (int j = 0; j < 4; ++j) {
                const int t = w * 16 + g * 4 + j;
                ldsT[cl * 64 + (t ^ sw)] = f2bf(acc[nt][j]);
            }
        }
        __syncthreads();

        const int b = row0 >> 10, t0 = row0 & 1023;
#pragma unroll
        for (int it = 0; it < 4; ++it) {
            const int slot = it * 256 + tid;      // 1024 chunks
            const int cl = slot >> 3, ch = slot & 7;
            const int colg = col0 + cl;
            const int h = colg >> 5, d = colg & 31;
            *(ushort8*)&Vt[(((size_t)(b * 8 + h)) * 32 + d) * 1024 + t0 + ch * 8] =
                *(const ushort8*)&ldsT[cl * 64 + ch * 8];
        }
    } else {
        float* xs = (float*)sm;                  // [32][256]
        float* cs = (float*)(sm + 32768);        // [8][256]
        const int rowg0 = (bid - 256) * 32;
        const bool is_src = rowg0 < NB * NS;
        const float* X = is_src ? (src + (size_t)rowg0 * NE)
                                : (trg + (size_t)(rowg0 - NB * NS) * NE);
        const float* C = is_src ? c_src : c_trg;
        float* S = is_src ? (ssrc + (size_t)rowg0 * NHEADS)
                          : (strg + (size_t)(rowg0 - NB * NS) * NHEADS);

#pragma unroll
        for (int it = 0; it < 8; ++it) {
            const int slot = it * 256 + tid;     // float4 slots
            const int row = slot >> 6, c4 = slot & 63;
            *(float4*)&xs[row * NE + c4 * 4] =
                *(const float4*)&X[(size_t)row * NE + c4 * 4];
            cs[slot] = C[slot];
        }
        __syncthreads();

        const int r = tid >> 3, h = tid & 7;
        float s = 0.f;
        for (int e = 0; e < NE; e += 4) {
            const float4 x = *(const float4*)&xs[r * NE + e];
            const float4 c = *(const float4*)&cs[h * NE + e];
            s += x.x * c.x + x.y * c.y + x.z * c.z + x.w * c.w;
        }
        S[(size_t)r * NHEADS + h] = s;
    }
}

// ---------------------------------------------------------------------------
// Kernel C: fused softmax + attn write + aggregation + out-GEMM.
// Block = (b, 16-row stile), ALL 8 heads. Grid 512, 4 waves.
// passA: wave w handles heads {2w, 2w+1} x 16 rows: exp2(leaky) -> bf16,
//        unnormalized MFMA vs Vt (global, L2-hot) + row sums.
// agg epilogue -> swizzled LDS bf16 tile [16][256].
// out-GEMM: 16x256x256 bf16 MFMA off LDS, waves split cols; writes out f32.
// passB: coalesced attn stores (rows sequential, 1KB/inst).
// ---------------------------------------------------------------------------
__global__ __launch_bounds__(256) void fused_kernel(
    const float* __restrict__ ssrc, const float* __restrict__ strg,
    const void* __restrict__ smask, const void* __restrict__ tmask,
    const int* __restrict__ flag_p, const unsigned short* __restrict__ Vt,
    const unsigned short* __restrict__ Wt_o,
    float* __restrict__ attn, float* __restrict__ out) {
    const int blk = blockIdx.x;
    const int q = blk & 63;            // 16-row stile
    const int b = blk >> 6;
    const int tid = threadIdx.x;
    const int lane = tid & 63;
    const int w = tid >> 6;
    const int flag = *flag_p;

    __shared__ __align__(16) float s_sm[8][1024];        // 32 KB
    __shared__ __align__(16) unsigned short agg_sw[16 * 256]; // 8 KB
    __shared__ float s_inv[8][16];
    __shared__ float s_ssv[8][16];

    // stage all 8 heads' masked strg*LOG2E (strg rows are 8 contiguous f32)
    for (int t = tid; t < NT; t += 256) {
        const bool mv = flag ? (((const int*)tmask)[b * NT + t] != 0)
                             : (((const unsigned char*)tmask)[b * NT + t] != 0);
        const float4 s0 = *(const float4*)&strg[((size_t)b * NT + t) * 8];
        const float4 s1 = *(const float4*)&strg[((size_t)b * NT + t) * 8 + 4];
        const float sv[8] = {s0.x, s0.y, s0.z, s0.w, s1.x, s1.y, s1.z, s1.w};
#pragma unroll
        for (int h = 0; h < 8; ++h)
            s_sm[h][t] = mv ? sv[h] * LOG2E : -1e30f;
    }
    __syncthreads();

    const int r = lane & 15;
    const int g = lane >> 4;
    const int srow = q * 16 + r;
    const bool rowv = flag ? (((const int*)smask)[b * NS + srow] != 0)
                           : (((const unsigned char*)smask)[b * NS + srow] != 0);
    const int sw = (r & 7) << 3;

    f32x4 acc0[2], acc1[2];

#pragma unroll
    for (int hh = 0; hh < 2; ++hh) {
        const int h = w * 2 + hh;
        const float ss2 = ssrc[((size_t)b * NS + srow) * NHEADS + h] * LOG2E;
        const unsigned short* vr0 = Vt + (size_t)(b * 8 + h) * 32768 + r * 1024;
        const unsigned short* vr1 = vr0 + 16 * 1024;
        f32x4 a0 = {0.f, 0.f, 0.f, 0.f};
        f32x4 a1 = {0.f, 0.f, 0.f, 0.f};
        float sum = 0.f;
#pragma unroll 4
        for (int c = 0; c < 32; ++c) {
            const int tb = c * 32 + g * 8;
            const short8 b0 = *(const short8*)&vr0[tb ^ sw];
            const short8 b1 = *(const short8*)&vr1[tb ^ sw];
            const float4 v0 = *(const float4*)&s_sm[h][tb];
            const float4 v1 = *(const float4*)&s_sm[h][tb + 4];
            const float vv[8] = {v0.x, v0.y, v0.z, v0.w, v1.x, v1.y, v1.z, v1.w};
            short8 pa;
#pragma unroll
            for (int e = 0; e < 8; ++e) {
                const float p = exp2_fast(leaky(ss2 + vv[e]));
                sum += p;
                pa[e] = (short)f2bf(p);
            }
            a0 = __builtin_amdgcn_mfma_f32_16x16x32_bf16(pa, b0, a0, 0, 0, 0);
            a1 = __builtin_amdgcn_mfma_f32_16x16x32_bf16(pa, b1, a1, 0, 0, 0);
        }
        sum += __shfl_xor(sum, 16);
        sum += __shfl_xor(sum, 32);
        const float inv = (rowv && sum > 0.f) ? 1.f / sum : 0.f;
        if (g == 0) {
            s_inv[h][r] = inv;
            s_ssv[h][r] = ss2;
        }
        acc0[hh] = a0;
        acc1[hh] = a1;
    }
    __syncthreads();   // s_inv / s_ssv ready

    // agg epilogue -> swizzled LDS bf16 (C layout: col=lane&15, row=g*4+j)
#pragma unroll
    for (int hh = 0; hh < 2; ++hh) {
        const int h = w * 2 + hh;
#pragma unroll
        for (int j = 0; j < 4; ++j) {
            const int row = g * 4 + j;
            const float iv = s_inv[h][row];
            int col = h * 32 + r;
            agg_sw[row * 256 + ((((col >> 3) ^ (row & 7)) << 3) | (col & 7))] =
                f2bf(acc0[hh][j] * iv);
            col += 16;
            agg_sw[row * 256 + ((((col >> 3) ^ (row & 7)) << 3) | (col & 7))] =
                f2bf(acc1[hh][j] * iv);
        }
    }
    __syncthreads();   // agg_sw ready

    // out-GEMM: 16 rows x 256 cols, K=256; wave w owns cols [w*64, w*64+64)
    f32x4 oacc[4];
#pragma unroll
    for (int nt = 0; nt < 4; ++nt) oacc[nt] = (f32x4){0.f, 0.f, 0.f, 0.f};
#pragma unroll
    for (int kk = 0; kk < 8; ++kk) {
        const short8 af = *(const short8*)&agg_sw[r * 256 + (((kk * 4 + g) ^ (r & 7)) * 8)];
#pragma unroll
        for (int nt = 0; nt < 4; ++nt) {
            const int col = w * 64 + nt * 16 + r;
            const short8 bf = *(const short8*)&Wt_o[(size_t)col * NE + kk * 32 + g * 8];
            oacc[nt] = __builtin_amdgcn_mfma_f32_16x16x32_bf16(af, bf, oacc[nt], 0, 0, 0);
        }
    }
#pragma unroll
    for (int nt = 0; nt < 4; ++nt) {
        const int col = w * 64 + nt * 16 + r;
#pragma unroll
        for (int j = 0; j < 4; ++j)
            out[((size_t)b * NS + q * 16 + g * 4 + j) * NE + col] = oacc[nt][j];
    }

    // passB: coalesced attn stores; 32 (head,row) pairs per wave
    for (int i = 0; i < 32; ++i) {
        const int idx = w * 32 + i;
        const int h = idx >> 4, rr = idx & 15;
        const float ssr = s_ssv[h][rr];
        const float ivr = s_inv[h][rr];
        float* arow = attn + ((size_t)(b * NHEADS + h) * NS + q * 16 + rr) * NT;
#pragma unroll
        for (int qq = 0; qq < 4; ++qq) {
            const int t0 = qq * 256 + lane * 4;
            const float4 sm4 = *(const float4*)&s_sm[h][t0];
            float4 o;
            o.x = exp2_fast(leaky(ssr + sm4.x)) * ivr;
            o.y = exp2_fast(leaky(ssr + sm4.y)) * ivr;
            o.z = exp2_fast(leaky(ssr + sm4.z)) * ivr;
            o.w = exp2_fast(leaky(ssr + sm4.w)) * ivr;
            *(float4*)&arow[t0] = o;
        }
    }
}

extern "C" void kernel_launch(void* const* d_in, const int* in_sizes, int n_in,
                              void* d_out, int out_size, void* d_ws, size_t ws_size,
                              hipStream_t stream) {
    const float* src   = (const float*)d_in[0];
    const float* trg   = (const float*)d_in[1];
    const void*  smask = d_in[2];
    const void*  tmask = d_in[3];
    const float* Wsrc  = (const float*)d_in[4];
    const float* Wtrg  = (const float*)d_in[5];
    const float* asrc  = (const float*)d_in[6];
    const float* atrg  = (const float*)d_in[7];
    const float* Wout  = (const float*)d_in[8];

    float* out  = (float*)d_out;
    float* attn = out + (size_t)NB * NS * NE;

    char* wsb = (char*)d_ws;
    unsigned short* Vt   = (unsigned short*)(wsb + O_VT);
    unsigned short* Wt_t = (unsigned short*)(wsb + O_WTT);
    unsigned short* Wt_o = (unsigned short*)(wsb + O_WTO);
    float* c_src = (float*)(wsb + O_CSRC);
    float* c_trg = (float*)(wsb + O_CTRG);
    float* ssrc  = (float*)(wsb + O_SSRC);
    float* strg  = (float*)(wsb + O_STRG);
    int*   flag  = (int*)(wsb + O_FLAG);

    setup_kernel<<<35, 256, 0, stream>>>(
        (const unsigned*)tmask, Wsrc, Wtrg, Wout, asrc, atrg,
        c_src, c_trg, Wt_t, Wt_o, flag);

    mid_kernel<<<768, 256, 0, stream>>>(
        src, trg, c_src, c_trg, Wt_t, Vt, ssrc, strg);

    fused_kernel<<<NB * (NS / 16), 256, 0, stream>>>(
        ssrc, strg, smask, tmask, flag, Vt, Wt_o, attn, out);
}